// Round 24
// baseline (7034.680 us; speedup 1.0000x reference)
//
#include <hip/hip_runtime.h>
#include <hip/hip_bf16.h>
#include <hip/hip_fp16.h>
#include <stdint.h>

#define K_NBR 32
#define EPS_F 1e-5f

typedef _Float16 half8v __attribute__((ext_vector_type(8)));
typedef _Float16 half4v __attribute__((ext_vector_type(4)));
typedef float float4v __attribute__((ext_vector_type(4)));

// ---------------------------------------------------------------------------
// FPS: EXACT verified arithmetic (asc-rn direct, smallest-index argmax).
// R18 scan structure; points cached in LDS planar arrays (no register spill,
// no dependent global load on the serial path). dist[] stays in registers.
// ---------------------------------------------------------------------------
template<int PPT>
__global__ __launch_bounds__(256) void fps_kernel(const float* __restrict__ p, int N, int S,
                                                  int* __restrict__ idx_out,
                                                  float* __restrict__ centers) {
    constexpr int CH = PPT / 4;
    constexpr int NPT = PPT * 256;
    const int b = blockIdx.x;
    const int tid = threadIdx.x;
    const float* pb = p + (size_t)b * N * 3;

    __shared__ float s_x[NPT];
    __shared__ float s_y[NPT];
    __shared__ float s_z[NPT];
    __shared__ float s_val[2][4];
    __shared__ int   s_idx[2][4];

    float dist[PPT];
    const float l0x = pb[0], l0y = pb[1], l0z = pb[2];
#pragma unroll
    for (int j = 0; j < PPT; ++j) {
        int i = j * 256 + tid;
        float x = pb[(size_t)i * 3 + 0];
        float y = pb[(size_t)i * 3 + 1];
        float z = pb[(size_t)i * 3 + 2];
        s_x[i] = x; s_y[i] = y; s_z[i] = z;
        float dx = __fsub_rn(x, l0x);
        float dy = __fsub_rn(y, l0y);
        float dz = __fsub_rn(z, l0z);
        dist[j] = __fadd_rn(__fadd_rn(__fmul_rn(dx, dx), __fmul_rn(dy, dy)), __fmul_rn(dz, dz));
    }

    if (tid == 0) {
        idx_out[(size_t)b * S] = 0;
        centers[((size_t)b * S) * 3 + 0] = l0x;
        centers[((size_t)b * S) * 3 + 1] = l0y;
        centers[((size_t)b * S) * 3 + 2] = l0z;
    }
    __syncthreads();

    for (int t = 1; t < S; ++t) {
        const int pp = t & 1;
        // 4 independent ascending chains ('>' keeps first = smallest index)
        float v[4]; int ix[4];
#pragma unroll
        for (int k = 0; k < 4; ++k) {
            v[k] = dist[k * CH]; ix[k] = (k * CH) * 256 + tid;
#pragma unroll
            for (int j = 1; j < CH; ++j) {
                if (dist[k * CH + j] > v[k]) { v[k] = dist[k * CH + j]; ix[k] = (k * CH + j) * 256 + tid; }
            }
        }
        float bv = v[0]; int bi = ix[0];
#pragma unroll
        for (int k = 1; k < 4; ++k) if (v[k] > bv) { bv = v[k]; bi = ix[k]; }
        // wave argmax (max value, min index tiebreak)
#pragma unroll
        for (int off = 32; off >= 1; off >>= 1) {
            float ov = __shfl_down(bv, off);
            int   oi = __shfl_down(bi, off);
            if (ov > bv || (ov == bv && oi < bi)) { bv = ov; bi = oi; }
        }
        if ((tid & 63) == 0) { s_val[pp][tid >> 6] = bv; s_idx[pp][tid >> 6] = bi; }
        __syncthreads();
        bv = s_val[pp][0]; bi = s_idx[pp][0];
#pragma unroll
        for (int w = 1; w < 4; ++w)
            if (s_val[pp][w] > bv || (s_val[pp][w] == bv && s_idx[pp][w] < bi)) { bv = s_val[pp][w]; bi = s_idx[pp][w]; }
        // winner coords: broadcast LDS reads (no global load on serial path)
        const float lx = s_x[bi];
        const float ly = s_y[bi];
        const float lz = s_z[bi];
        if (tid == 0) {
            idx_out[(size_t)b * S + t] = bi;
            centers[((size_t)b * S + t) * 3 + 0] = lx;
            centers[((size_t)b * S + t) * 3 + 1] = ly;
            centers[((size_t)b * S + t) * 3 + 2] = lz;
        }
#pragma unroll
        for (int j = 0; j < PPT; ++j) {
            int i = j * 256 + tid;
            float dx = __fsub_rn(s_x[i], lx);
            float dy = __fsub_rn(s_y[i], ly);
            float dz = __fsub_rn(s_z[i], lz);
            float nd = __fadd_rn(__fadd_rn(__fmul_rn(dx, dx), __fmul_rn(dy, dy)), __fmul_rn(dz, dz));
            dist[j] = fminf(dist[j], nd);
        }
    }
}

// ---------------------------------------------------------------------------
// Ball query — BYTE-IDENTICAL to the passing round-17 kernel. DO NOT TOUCH.
// ---------------------------------------------------------------------------
__global__ __launch_bounds__(256) void ball_query_kernel(const float* __restrict__ pts,
                                                         const float* __restrict__ ctr,
                                                         int N, int S, int* __restrict__ nbr) {
    int gw   = (int)((blockIdx.x * 256 + threadIdx.x) >> 6);
    int lane = threadIdx.x & 63;
    int b = gw / S;
    int s = gw - b * S;
    const float* pb = pts + (size_t)b * N * 3;
    const float c0 = ctr[((size_t)b * S + s) * 3 + 0];
    const float c1 = ctr[((size_t)b * S + s) * 3 + 1];
    const float c2 = ctr[((size_t)b * S + s) * 3 + 2];
    const float cn = __fadd_rn(__fadd_rn(__fmul_rn(c0, c0), __fmul_rn(c2, c2)), __fmul_rn(c1, c1));
    const float R2 = (float)(0.1 * 0.1);
    int* out = nbr + (size_t)gw * K_NBR;

    int cnt = 0;
    int firstIdx = 0;
    bool haveFirst = false;
    for (int base = 0; base < N && cnt < K_NBR; base += 64) {
        int i = base + lane;
        float x = pb[(size_t)i * 3 + 0];
        float y = pb[(size_t)i * 3 + 1];
        float z = pb[(size_t)i * 3 + 2];
        float pn = __fadd_rn(__fadd_rn(__fmul_rn(x, x), __fmul_rn(z, z)), __fmul_rn(y, y));
        float pr0 = __fmul_rn(c0, x);
        float pr1 = __fmul_rn(c1, y);
        float pr2 = __fmul_rn(c2, z);
        float dt  = __fadd_rn(__fadd_rn(pr0, pr2), pr1);
        float d2 = __fsub_rn(__fadd_rn(cn, pn), __fmul_rn(2.0f, dt));
        bool inR = d2 < R2;
        unsigned long long mask = __ballot(inR);
        if (mask) {
            if (!haveFirst) { haveFirst = true; firstIdx = base + __builtin_ctzll(mask); }
            int rank = __popcll(mask & ((1ull << lane) - 1ull));
            if (inR) {
                int slot = cnt + rank;
                if (slot < K_NBR) out[slot] = i;
            }
            cnt += (int)__popcll(mask);
        }
    }
    if (cnt < K_NBR) {
        for (int sl = cnt + lane; sl < K_NBR; sl += 64) out[sl] = firstIdx;
    }
}

// ---------------------------------------------------------------------------
__global__ void gather_cf_kernel(const float* __restrict__ f_b, const int* __restrict__ idx_b,
                                 int N, int S, float* __restrict__ cf, int total) {
    int i = blockIdx.x * 256 + threadIdx.x;
    if (i >= total) return;
    int s = i % S;
    int c = i / S;
    cf[i] = f_b[(size_t)c * N + idx_b[s]];
}

__global__ void build_x_kernel(const float* __restrict__ p_b, const float* __restrict__ f_b,
                               const float* __restrict__ ctr_b, const float* __restrict__ cf,
                               const int* __restrict__ nbr_b,
                               int N, int S, int C, int Cin_pad, int M,
                               _Float16* __restrict__ x) {
    int m = blockIdx.x * 256 + threadIdx.x;
    if (m >= M) return;
    int s = m / K_NBR;
    int n = nbr_b[m];
    const float* pp = p_b + (size_t)n * 3;
    const float* cc = ctr_b + (size_t)s * 3;
    _Float16* row = x + (size_t)m * Cin_pad;
    row[0] = (_Float16)__fsub_rn(pp[0], cc[0]);
    row[1] = (_Float16)__fsub_rn(pp[1], cc[1]);
    row[2] = (_Float16)__fsub_rn(pp[2], cc[2]);
    for (int c = 0; c < C; ++c)
        row[3 + c] = (_Float16)__fsub_rn(f_b[(size_t)c * N + n], cf[(size_t)c * S + s]);
    for (int c = 3 + C; c < Cin_pad; ++c) row[c] = (_Float16)0.f;
}

__global__ void gather_cf2_kernel(const _Float16* __restrict__ ftr, const int* __restrict__ idx_b,
                                  int C, int S, _Float16* __restrict__ cfh, int total) {
    int i = blockIdx.x * 256 + threadIdx.x;
    if (i >= total) return;
    int c = i % C;
    int s = i / C;
    cfh[i] = ftr[(size_t)idx_b[s] * C + c];
}

__global__ void build_x2_kernel(const float* __restrict__ p_b, const _Float16* __restrict__ ftr,
                                const float* __restrict__ ctr_b, const _Float16* __restrict__ cfh,
                                const int* __restrict__ nbr_b,
                                int S, int C, int Cin_pad, int M,
                                _Float16* __restrict__ x) {
    int m = blockIdx.x * 256 + threadIdx.x;
    if (m >= M) return;
    int s = m / K_NBR;
    int n = nbr_b[m];
    const float* pp = p_b + (size_t)n * 3;
    const float* cc = ctr_b + (size_t)s * 3;
    _Float16* row = x + (size_t)m * Cin_pad;
    row[0] = (_Float16)__fsub_rn(pp[0], cc[0]);
    row[1] = (_Float16)__fsub_rn(pp[1], cc[1]);
    row[2] = (_Float16)__fsub_rn(pp[2], cc[2]);
    const _Float16* fr = ftr + (size_t)n * C;
    const _Float16* cr = cfh + (size_t)s * C;
    for (int c = 0; c < C; ++c)
        row[3 + c] = (_Float16)__fsub_rn((float)fr[c], (float)cr[c]);
    for (int c = 3 + C; c < Cin_pad; ++c) row[c] = (_Float16)0.f;
}

__global__ void wconv_kernel(const float* __restrict__ W, int Cin, int Cin_pad,
                             _Float16* __restrict__ Wh, int total) {
    int i = blockIdx.x * 256 + threadIdx.x;
    if (i >= total) return;
    int o = i / Cin_pad, c = i - o * Cin_pad;
    Wh[i] = (c < Cin) ? (_Float16)W[(size_t)o * Cin + c] : (_Float16)0.f;
}

// ---------------------------------------------------------------------------
// MFMA conv with fused IN (stats epilogue + norm-on-load).
// ---------------------------------------------------------------------------
template<bool HAS_POOL, bool NORM_IN, bool STATS>
__global__ __launch_bounds__(256) void conv_mfma_kernel(
    const _Float16* __restrict__ Wh, const float* __restrict__ bias,
    int Cin_pad, int C1,
    const _Float16* __restrict__ Xp,
    const _Float16* __restrict__ X,
    const float* __restrict__ muIn, const float* __restrict__ riIn,
    _Float16* __restrict__ Y,
    int M, int Cout,
    float* __restrict__ psum, float* __restrict__ psq) {
    const int wave = threadIdx.x >> 6;
    const int lane = threadIdx.x & 63;
    const int row  = lane & 15;
    const int kg   = lane >> 4;
    const int m0   = blockIdx.x * 128 + wave * 32;
    const int o0   = blockIdx.y * 64;
    const int mIdx0 = m0 + row;
    const int mIdx1 = m0 + 16 + row;

    float4v acc[2][4];
#pragma unroll
    for (int t = 0; t < 4; ++t) {
        const float* bp = bias + o0 + 16 * t + kg * 4;
        float4v bv4 = (float4v){bp[0], bp[1], bp[2], bp[3]};
        acc[0][t] = bv4;
        acc[1][t] = bv4;
    }
    const int C2 = Cin_pad - C1;
    if (HAS_POOL) {
        const _Float16* pr0 = Xp + (size_t)(mIdx0 >> 5) * C1;
        const _Float16* pr1 = Xp + (size_t)(mIdx1 >> 5) * C1;
        for (int c0 = 0; c0 < C1; c0 += 32) {
            half8v b0 = *(const half8v*)(pr0 + c0 + kg * 8);
            half8v b1 = *(const half8v*)(pr1 + c0 + kg * 8);
#pragma unroll
            for (int t = 0; t < 4; ++t) {
                half8v afr = *(const half8v*)(Wh + (size_t)(o0 + 16 * t + row) * Cin_pad + c0 + kg * 8);
                acc[0][t] = __builtin_amdgcn_mfma_f32_16x16x32_f16(afr, b0, acc[0][t], 0, 0, 0);
                acc[1][t] = __builtin_amdgcn_mfma_f32_16x16x32_f16(afr, b1, acc[1][t], 0, 0, 0);
            }
        }
    }
    const _Float16* xr0 = X + (size_t)mIdx0 * C2;
    const _Float16* xr1 = X + (size_t)mIdx1 * C2;
    for (int c0 = 0; c0 < C2; c0 += 32) {
        half8v b0 = *(const half8v*)(xr0 + c0 + kg * 8);
        half8v b1 = *(const half8v*)(xr1 + c0 + kg * 8);
        if (NORM_IN) {
            const int cb = c0 + kg * 8;
#pragma unroll
            for (int r = 0; r < 8; ++r) {
                float mu = muIn[cb + r], ri = riIn[cb + r];
                b0[r] = (_Float16)fmaxf(((float)b0[r] - mu) * ri, 0.f);
                b1[r] = (_Float16)fmaxf(((float)b1[r] - mu) * ri, 0.f);
            }
        }
#pragma unroll
        for (int t = 0; t < 4; ++t) {
            half8v afr = *(const half8v*)(Wh + (size_t)(o0 + 16 * t + row) * Cin_pad + C1 + c0 + kg * 8);
            acc[0][t] = __builtin_amdgcn_mfma_f32_16x16x32_f16(afr, b0, acc[0][t], 0, 0, 0);
            acc[1][t] = __builtin_amdgcn_mfma_f32_16x16x32_f16(afr, b1, acc[1][t], 0, 0, 0);
        }
    }
#pragma unroll
    for (int w = 0; w < 2; ++w) {
        int mi = (w == 0) ? mIdx0 : mIdx1;
#pragma unroll
        for (int t = 0; t < 4; ++t) {
            half4v hv;
            hv[0] = (_Float16)acc[w][t][0];
            hv[1] = (_Float16)acc[w][t][1];
            hv[2] = (_Float16)acc[w][t][2];
            hv[3] = (_Float16)acc[w][t][3];
            *(half4v*)(Y + (size_t)mi * Cout + o0 + 16 * t + kg * 4) = hv;
        }
    }
    if (STATS) {
        float s[16], q[16];
#pragma unroll
        for (int t = 0; t < 4; ++t)
#pragma unroll
            for (int r = 0; r < 4; ++r) {
                float a0 = acc[0][t][r], a1 = acc[1][t][r];
                s[t * 4 + r] = a0 + a1;
                q[t * 4 + r] = fmaf(a0, a0, a1 * a1);
            }
#pragma unroll
        for (int mask = 1; mask <= 8; mask <<= 1) {
#pragma unroll
            for (int i = 0; i < 16; ++i) {
                s[i] += __shfl_xor(s[i], mask);
                q[i] += __shfl_xor(q[i], mask);
            }
        }
        if (row == 0) {
            int mrow = blockIdx.x * 4 + wave;
            float* ps = psum + (size_t)mrow * Cout + o0;
            float* pq = psq  + (size_t)mrow * Cout + o0;
#pragma unroll
            for (int t = 0; t < 4; ++t)
#pragma unroll
                for (int r = 0; r < 4; ++r) {
                    ps[16 * t + kg * 4 + r] = s[t * 4 + r];
                    pq[16 * t + kg * 4 + r] = q[t * 4 + r];
                }
        }
    }
}

// in_fin: one BLOCK per channel; deterministic tree reduce.
__global__ __launch_bounds__(256) void in_fin_kernel(const float* __restrict__ psum,
                                                     const float* __restrict__ psq,
                                                     int C, int rows, int M,
                                                     float* __restrict__ mean,
                                                     float* __restrict__ rinv) {
    int c = blockIdx.x;
    int tid = threadIdx.x;
    float s = 0.f, q = 0.f;
    for (int r = tid; r < rows; r += 256) {
        s += psum[(size_t)r * C + c];
        q += psq [(size_t)r * C + c];
    }
#pragma unroll
    for (int off = 32; off >= 1; off >>= 1) {
        s += __shfl_down(s, off);
        q += __shfl_down(q, off);
    }
    __shared__ float sS[4], sQ[4];
    if ((tid & 63) == 0) { sS[tid >> 6] = s; sQ[tid >> 6] = q; }
    __syncthreads();
    if (tid == 0) {
        float fs = sS[0] + sS[1] + sS[2] + sS[3];
        float fq = sQ[0] + sQ[1] + sQ[2] + sQ[3];
        float mu  = fs / (float)M;
        float var = fq / (float)M - mu * mu;
        mean[c] = mu;
        rinv[c] = rsqrtf(fmaxf(var, 0.f) + EPS_F);
    }
}

// pooled[s][c] = max_k Y[(s*32+k)][c]
__global__ void maxk_kernel(const _Float16* __restrict__ Y, int C,
                            _Float16* __restrict__ pooled, int total) {
    int i = blockIdx.x * 256 + threadIdx.x;
    if (i >= total) return;
    int c = i % C;
    int s = i / C;
    const _Float16* base = Y + (size_t)s * 32 * C + c;
    float mx = (float)base[0];
#pragma unroll 8
    for (int k = 1; k < K_NBR; ++k) mx = fmaxf(mx, (float)base[(size_t)k * C]);
    pooled[(size_t)s * C + c] = (_Float16)mx;
}

// out_f[o][s] = relu((max_k RD - mu)*rinv); + f16 transposed feature copy.
__global__ void maxk_out_in_kernel(const _Float16* __restrict__ Y, int C, int S,
                                   const float* __restrict__ mean, const float* __restrict__ rinv,
                                   float* __restrict__ outf_b, _Float16* __restrict__ ftr_out,
                                   int total) {
    int i = blockIdx.x * 256 + threadIdx.x;
    if (i >= total) return;
    int o = i % C;
    int s = i / C;
    const _Float16* base = Y + (size_t)s * 32 * C + o;
    float mx = (float)base[0];
#pragma unroll 8
    for (int k = 1; k < K_NBR; ++k) mx = fmaxf(mx, (float)base[(size_t)k * C]);
    float val = fmaxf((mx - mean[o]) * rinv[o], 0.f);
    outf_b[(size_t)o * S + s] = val;
    if (ftr_out) ftr_out[i] = (_Float16)val;
}

// ---------------------------------------------------------------------------
struct StageArgs {
    const float *P, *F, *CTR;
    const _Float16* FTR;
    const int *NBR, *IDX;
    int N, S, C, e, Cin_pad;
    const _Float16 *Wa1, *Wb1, *Wa2, *Wb2;
    const float *ba1, *bb1, *ba2, *bb2;
    float* OUTF;
    _Float16* FTR_OUT;
};

static void run_conv_stage(const StageArgs& a, hipStream_t stream,
                           uint8_t* R1, uint8_t* R2, size_t xo_off,
                           _Float16* pooled, float* cf_ws, _Float16* cfh_ws,
                           float* psum, float* psq, float* mean_ws, float* rinv_ws) {
    const int M = a.S * K_NBR;
    const int e = a.e;
    const int srows = M / 32;
    _Float16* x0 = (_Float16*)R1;
    _Float16* RA = (_Float16*)(R1 + xo_off);
    _Float16* RC = (_Float16*)R1;
    _Float16* RB = (_Float16*)R2;
    _Float16* RD = (_Float16*)R2;
    for (int b = 0; b < 4; ++b) {
        const float* p_b   = a.P + (size_t)b * a.N * 3;
        const float* ctr_b = a.CTR + (size_t)b * a.S * 3;
        const int*   nbr_b = a.NBR + (size_t)b * a.S * K_NBR;
        const int*   idx_b = a.IDX + (size_t)b * a.S;
        float*       outf_b= a.OUTF + (size_t)b * e * a.S;

        if (a.FTR == nullptr) {
            const float* f_b = a.F + (size_t)b * a.C * a.N;
            gather_cf_kernel<<<(a.C * a.S + 255) / 256, 256, 0, stream>>>(f_b, idx_b, a.N, a.S, cf_ws, a.C * a.S);
            build_x_kernel<<<M / 256, 256, 0, stream>>>(p_b, f_b, ctr_b, cf_ws, nbr_b,
                                                        a.N, a.S, a.C, a.Cin_pad, M, x0);
        } else {
            const _Float16* ftr_b = a.FTR + (size_t)b * a.N * a.C;
            gather_cf2_kernel<<<(a.C * a.S + 255) / 256, 256, 0, stream>>>(ftr_b, idx_b, a.C, a.S, cfh_ws, a.C * a.S);
            build_x2_kernel<<<M / 256, 256, 0, stream>>>(p_b, ftr_b, ctr_b, cfh_ws, nbr_b,
                                                         a.S, a.C, a.Cin_pad, M, x0);
        }

        conv_mfma_kernel<false, false, true><<<dim3(M / 128, e / 64), 256, 0, stream>>>(
            a.Wa1, a.ba1, a.Cin_pad, 0, nullptr, x0, nullptr, nullptr, RA, M, e, psum, psq);
        in_fin_kernel<<<e, 256, 0, stream>>>(psum, psq, e, srows, M, mean_ws, rinv_ws);
        conv_mfma_kernel<false, true, false><<<dim3(M / 128, e / 64), 256, 0, stream>>>(
            a.Wb1, a.bb1, e, 0, nullptr, RA, mean_ws, rinv_ws, RB, M, e, nullptr, nullptr);
        maxk_kernel<<<(e * (M / 32) + 255) / 256, 256, 0, stream>>>(RB, e, pooled, e * (M / 32));
        conv_mfma_kernel<true, false, true><<<dim3(M / 128, (2 * e) / 64), 256, 0, stream>>>(
            a.Wa2, a.ba2, 2 * e, e, pooled, RB, nullptr, nullptr, RC, M, 2 * e, psum, psq);
        in_fin_kernel<<<2 * e, 256, 0, stream>>>(psum, psq, 2 * e, srows, M, mean_ws, rinv_ws);
        conv_mfma_kernel<false, true, true><<<dim3(M / 128, e / 64), 256, 0, stream>>>(
            a.Wb2, a.bb2, 2 * e, 0, nullptr, RC, mean_ws, rinv_ws, RD, M, e, psum, psq);
        in_fin_kernel<<<e, 256, 0, stream>>>(psum, psq, e, srows, M, mean_ws, rinv_ws);
        _Float16* ftr_b_out = a.FTR_OUT ? a.FTR_OUT + (size_t)b * a.S * e : nullptr;
        maxk_out_in_kernel<<<(e * a.S + 255) / 256, 256, 0, stream>>>(RD, e, a.S, mean_ws, rinv_ws,
                                                                      outf_b, ftr_b_out, e * a.S);
    }
}

extern "C" void kernel_launch(void* const* d_in, const int* in_sizes, int n_in,
                              void* d_out, int out_size, void* d_ws, size_t ws_size,
                              hipStream_t stream) {
    const float* p    = (const float*)d_in[0];
    const float* f    = (const float*)d_in[1];
    const float* w1a1 = (const float*)d_in[2];
    const float* b1a1 = (const float*)d_in[3];
    const float* w1b1 = (const float*)d_in[4];
    const float* b1b1 = (const float*)d_in[5];
    const float* w1a2 = (const float*)d_in[6];
    const float* b1a2 = (const float*)d_in[7];
    const float* w1b2 = (const float*)d_in[8];
    const float* b1b2 = (const float*)d_in[9];
    const float* w2a1 = (const float*)d_in[10];
    const float* b2a1 = (const float*)d_in[11];
    const float* w2b1 = (const float*)d_in[12];
    const float* b2b1 = (const float*)d_in[13];
    const float* w2a2 = (const float*)d_in[14];
    const float* b2a2 = (const float*)d_in[15];
    const float* w2b2 = (const float*)d_in[16];
    const float* b2b2 = (const float*)d_in[17];

    float* out   = (float*)d_out;
    float* outp1 = out;
    float* outf1 = out + 24576;
    float* outp2 = outf1 + 1572864;
    float* outf2 = outp2 + 6144;

    uint8_t* wsp = (uint8_t*)d_ws;
    uint8_t* wend = wsp + ws_size;
    auto alloc = [&](size_t bytes) -> void* {
        void* r = wsp;
        wsp += (bytes + 255) & ~(size_t)255;
        return r;
    };
    int*   idx1   = (int*)  alloc((size_t)4 * 2048 * 4);
    int*   idx2   = (int*)  alloc((size_t)4 * 512 * 4);
    int*   nbr1   = (int*)  alloc((size_t)4 * 2048 * K_NBR * 4);
    int*   nbr2   = (int*)  alloc((size_t)4 * 512 * K_NBR * 4);
    float* cf_ws  = (float*)alloc((size_t)192 * 512 * 4);
    _Float16* cfh_ws = (_Float16*)alloc((size_t)512 * 192 * 2);
    float* mean_ws= (float*)alloc((size_t)768 * 4);
    float* rinv_ws= (float*)alloc((size_t)768 * 4);
    float* psum   = (float*)alloc((size_t)2048 * 768 * 4);
    float* psq    = (float*)alloc((size_t)2048 * 768 * 4);
    _Float16* pooled = (_Float16*)alloc((size_t)2048 * 384 * 2);
    _Float16* ftr1   = (_Float16*)alloc((size_t)4 * 2048 * 192 * 2);
    _Float16* h1a1 = (_Float16*)alloc((size_t)192 * 32  * 2);
    _Float16* h1b1 = (_Float16*)alloc((size_t)192 * 192 * 2);
    _Float16* h1a2 = (_Float16*)alloc((size_t)384 * 384 * 2);
    _Float16* h1b2 = (_Float16*)alloc((size_t)192 * 384 * 2);
    _Float16* h2a1 = (_Float16*)alloc((size_t)384 * 224 * 2);
    _Float16* h2b1 = (_Float16*)alloc((size_t)384 * 384 * 2);
    _Float16* h2a2 = (_Float16*)alloc((size_t)768 * 768 * 2);
    _Float16* h2b2 = (_Float16*)alloc((size_t)384 * 768 * 2);
    if (wsp > wend) return;

    auto wc = [&](const float* W, int Cin, int Cpad, int Cout, _Float16* Wh) {
        int tot = Cout * Cpad;
        wconv_kernel<<<(tot + 255) / 256, 256, 0, stream>>>(W, Cin, Cpad, Wh, tot);
    };
    wc(w1a1, 6,   32,  192, h1a1);
    wc(w1b1, 192, 192, 192, h1b1);
    wc(w1a2, 384, 384, 384, h1a2);
    wc(w1b2, 384, 384, 192, h1b2);
    wc(w2a1, 195, 224, 384, h2a1);
    wc(w2b1, 384, 384, 384, h2b1);
    wc(w2a2, 768, 768, 768, h2a2);
    wc(w2b2, 768, 768, 384, h2b2);

    // geometry: verified-exact FPS (LDS point cache) + frozen ball query
    fps_kernel<32><<<4, 256, 0, stream>>>(p, 8192, 2048, idx1, outp1);
    ball_query_kernel<<<(4 * 2048) / 4, 256, 0, stream>>>(p, outp1, 8192, 2048, nbr1);
    fps_kernel<8><<<4, 256, 0, stream>>>(outp1, 2048, 512, idx2, outp2);
    ball_query_kernel<<<(4 * 512) / 4, 256, 0, stream>>>(outp1, outp2, 2048, 512, nbr2);

    const size_t MB = (size_t)1024 * 1024;
    uint8_t* R1 = (uint8_t*)alloc(48 * MB);
    uint8_t* R2 = (uint8_t*)alloc(24 * MB);
    if (wsp > wend) return;

    StageArgs s1 { p, f, outp1, nullptr, nbr1, idx1, 8192, 2048, 3, 192, 32,
                   h1a1, h1b1, h1a2, h1b2, b1a1, b1b1, b1a2, b1b2, outf1, ftr1 };
    StageArgs s2 { outp1, nullptr, outp2, ftr1, nbr2, idx2, 2048, 512, 192, 384, 224,
                   h2a1, h2b1, h2a2, h2b2, b2a1, b2b1, b2a2, b2b2, outf2, nullptr };

    run_conv_stage(s1, stream, R1, R2, 8 * MB, pooled, cf_ws, cfh_ws, psum, psq, mean_ws, rinv_ws);
    run_conv_stage(s2, stream, R1, R2, 8 * MB, pooled, cf_ws, cfh_ws, psum, psq, mean_ws, rinv_ws);
}

// Round 25
// 5915.564 us; speedup vs baseline: 1.1892x; 1.1892x over previous
//
#include <hip/hip_runtime.h>
#include <hip/hip_bf16.h>
#include <hip/hip_fp16.h>
#include <stdint.h>

#define K_NBR 32
#define EPS_F 1e-5f

typedef _Float16 half8v __attribute__((ext_vector_type(8)));
typedef _Float16 half4v __attribute__((ext_vector_type(4)));
typedef float float4v __attribute__((ext_vector_type(4)));

// ---------------------------------------------------------------------------
// FPS: EXACT verified arithmetic (asc-rn direct, smallest-index argmax).
// R18 register structure. MINW template arg -> __launch_bounds__(256, MINW):
// stage 1 uses MINW=1 so the allocator can keep all 128 data floats in
// registers (only 4 blocks chip-wide; occupancy is irrelevant, spill is not).
// ---------------------------------------------------------------------------
template<int PPT, int MINW>
__global__ __launch_bounds__(256, MINW) void fps_kernel(const float* __restrict__ p, int N, int S,
                                                        int* __restrict__ idx_out,
                                                        float* __restrict__ centers) {
    constexpr int CH = PPT / 4;
    const int b = blockIdx.x;
    const int tid = threadIdx.x;
    const float* pb = p + (size_t)b * N * 3;

    float px[PPT], py[PPT], pz[PPT], dist[PPT];
    const float l0x = pb[0], l0y = pb[1], l0z = pb[2];
#pragma unroll
    for (int j = 0; j < PPT; ++j) {
        int i = j * 256 + tid;
        px[j] = pb[(size_t)i * 3 + 0];
        py[j] = pb[(size_t)i * 3 + 1];
        pz[j] = pb[(size_t)i * 3 + 2];
        float dx = __fsub_rn(px[j], l0x);
        float dy = __fsub_rn(py[j], l0y);
        float dz = __fsub_rn(pz[j], l0z);
        dist[j] = __fadd_rn(__fadd_rn(__fmul_rn(dx, dx), __fmul_rn(dy, dy)), __fmul_rn(dz, dz));
    }

    __shared__ float s_val[2][4];
    __shared__ int   s_idx[2][4];

    if (tid == 0) {
        idx_out[(size_t)b * S] = 0;
        centers[((size_t)b * S) * 3 + 0] = l0x;
        centers[((size_t)b * S) * 3 + 1] = l0y;
        centers[((size_t)b * S) * 3 + 2] = l0z;
    }

    for (int t = 1; t < S; ++t) {
        const int pp = t & 1;
        float v[4]; int ix[4];
#pragma unroll
        for (int k = 0; k < 4; ++k) {
            v[k] = dist[k * CH]; ix[k] = (k * CH) * 256 + tid;
#pragma unroll
            for (int j = 1; j < CH; ++j) {
                if (dist[k * CH + j] > v[k]) { v[k] = dist[k * CH + j]; ix[k] = (k * CH + j) * 256 + tid; }
            }
        }
        float bv = v[0]; int bi = ix[0];
#pragma unroll
        for (int k = 1; k < 4; ++k) if (v[k] > bv) { bv = v[k]; bi = ix[k]; }
#pragma unroll
        for (int off = 32; off >= 1; off >>= 1) {
            float ov = __shfl_down(bv, off);
            int   oi = __shfl_down(bi, off);
            if (ov > bv || (ov == bv && oi < bi)) { bv = ov; bi = oi; }
        }
        if ((tid & 63) == 0) { s_val[pp][tid >> 6] = bv; s_idx[pp][tid >> 6] = bi; }
        __syncthreads();
        bv = s_val[pp][0]; bi = s_idx[pp][0];
#pragma unroll
        for (int w = 1; w < 4; ++w)
            if (s_val[pp][w] > bv || (s_val[pp][w] == bv && s_idx[pp][w] < bi)) { bv = s_val[pp][w]; bi = s_idx[pp][w]; }
        const float lx = pb[(size_t)bi * 3 + 0];
        const float ly = pb[(size_t)bi * 3 + 1];
        const float lz = pb[(size_t)bi * 3 + 2];
        if (tid == 0) {
            idx_out[(size_t)b * S + t] = bi;
            centers[((size_t)b * S + t) * 3 + 0] = lx;
            centers[((size_t)b * S + t) * 3 + 1] = ly;
            centers[((size_t)b * S + t) * 3 + 2] = lz;
        }
#pragma unroll
        for (int j = 0; j < PPT; ++j) {
            float dx = __fsub_rn(px[j], lx);
            float dy = __fsub_rn(py[j], ly);
            float dz = __fsub_rn(pz[j], lz);
            float nd = __fadd_rn(__fadd_rn(__fmul_rn(dx, dx), __fmul_rn(dy, dy)), __fmul_rn(dz, dz));
            dist[j] = fminf(dist[j], nd);
        }
    }
}

// ---------------------------------------------------------------------------
// Ball query — BYTE-IDENTICAL to the passing round-17 kernel. DO NOT TOUCH.
// ---------------------------------------------------------------------------
__global__ __launch_bounds__(256) void ball_query_kernel(const float* __restrict__ pts,
                                                         const float* __restrict__ ctr,
                                                         int N, int S, int* __restrict__ nbr) {
    int gw   = (int)((blockIdx.x * 256 + threadIdx.x) >> 6);
    int lane = threadIdx.x & 63;
    int b = gw / S;
    int s = gw - b * S;
    const float* pb = pts + (size_t)b * N * 3;
    const float c0 = ctr[((size_t)b * S + s) * 3 + 0];
    const float c1 = ctr[((size_t)b * S + s) * 3 + 1];
    const float c2 = ctr[((size_t)b * S + s) * 3 + 2];
    const float cn = __fadd_rn(__fadd_rn(__fmul_rn(c0, c0), __fmul_rn(c2, c2)), __fmul_rn(c1, c1));
    const float R2 = (float)(0.1 * 0.1);
    int* out = nbr + (size_t)gw * K_NBR;

    int cnt = 0;
    int firstIdx = 0;
    bool haveFirst = false;
    for (int base = 0; base < N && cnt < K_NBR; base += 64) {
        int i = base + lane;
        float x = pb[(size_t)i * 3 + 0];
        float y = pb[(size_t)i * 3 + 1];
        float z = pb[(size_t)i * 3 + 2];
        float pn = __fadd_rn(__fadd_rn(__fmul_rn(x, x), __fmul_rn(z, z)), __fmul_rn(y, y));
        float pr0 = __fmul_rn(c0, x);
        float pr1 = __fmul_rn(c1, y);
        float pr2 = __fmul_rn(c2, z);
        float dt  = __fadd_rn(__fadd_rn(pr0, pr2), pr1);
        float d2 = __fsub_rn(__fadd_rn(cn, pn), __fmul_rn(2.0f, dt));
        bool inR = d2 < R2;
        unsigned long long mask = __ballot(inR);
        if (mask) {
            if (!haveFirst) { haveFirst = true; firstIdx = base + __builtin_ctzll(mask); }
            int rank = __popcll(mask & ((1ull << lane) - 1ull));
            if (inR) {
                int slot = cnt + rank;
                if (slot < K_NBR) out[slot] = i;
            }
            cnt += (int)__popcll(mask);
        }
    }
    if (cnt < K_NBR) {
        for (int sl = cnt + lane; sl < K_NBR; sl += 64) out[sl] = firstIdx;
    }
}

// ---------------------------------------------------------------------------
__global__ void gather_cf_kernel(const float* __restrict__ f_b, const int* __restrict__ idx_b,
                                 int N, int S, float* __restrict__ cf, int total) {
    int i = blockIdx.x * 256 + threadIdx.x;
    if (i >= total) return;
    int s = i % S;
    int c = i / S;
    cf[i] = f_b[(size_t)c * N + idx_b[s]];
}

__global__ void build_x_kernel(const float* __restrict__ p_b, const float* __restrict__ f_b,
                               const float* __restrict__ ctr_b, const float* __restrict__ cf,
                               const int* __restrict__ nbr_b,
                               int N, int S, int C, int Cin_pad, int M,
                               _Float16* __restrict__ x) {
    int m = blockIdx.x * 256 + threadIdx.x;
    if (m >= M) return;
    int s = m / K_NBR;
    int n = nbr_b[m];
    const float* pp = p_b + (size_t)n * 3;
    const float* cc = ctr_b + (size_t)s * 3;
    _Float16* row = x + (size_t)m * Cin_pad;
    row[0] = (_Float16)__fsub_rn(pp[0], cc[0]);
    row[1] = (_Float16)__fsub_rn(pp[1], cc[1]);
    row[2] = (_Float16)__fsub_rn(pp[2], cc[2]);
    for (int c = 0; c < C; ++c)
        row[3 + c] = (_Float16)__fsub_rn(f_b[(size_t)c * N + n], cf[(size_t)c * S + s]);
    for (int c = 3 + C; c < Cin_pad; ++c) row[c] = (_Float16)0.f;
}

__global__ void gather_cf2_kernel(const _Float16* __restrict__ ftr, const int* __restrict__ idx_b,
                                  int C, int S, _Float16* __restrict__ cfh, int total) {
    int i = blockIdx.x * 256 + threadIdx.x;
    if (i >= total) return;
    int c = i % C;
    int s = i / C;
    cfh[i] = ftr[(size_t)idx_b[s] * C + c];
}

__global__ void build_x2_kernel(const float* __restrict__ p_b, const _Float16* __restrict__ ftr,
                                const float* __restrict__ ctr_b, const _Float16* __restrict__ cfh,
                                const int* __restrict__ nbr_b,
                                int S, int C, int Cin_pad, int M,
                                _Float16* __restrict__ x) {
    int m = blockIdx.x * 256 + threadIdx.x;
    if (m >= M) return;
    int s = m / K_NBR;
    int n = nbr_b[m];
    const float* pp = p_b + (size_t)n * 3;
    const float* cc = ctr_b + (size_t)s * 3;
    _Float16* row = x + (size_t)m * Cin_pad;
    row[0] = (_Float16)__fsub_rn(pp[0], cc[0]);
    row[1] = (_Float16)__fsub_rn(pp[1], cc[1]);
    row[2] = (_Float16)__fsub_rn(pp[2], cc[2]);
    const _Float16* fr = ftr + (size_t)n * C;
    const _Float16* cr = cfh + (size_t)s * C;
    for (int c = 0; c < C; ++c)
        row[3 + c] = (_Float16)__fsub_rn((float)fr[c], (float)cr[c]);
    for (int c = 3 + C; c < Cin_pad; ++c) row[c] = (_Float16)0.f;
}

__global__ void wconv_kernel(const float* __restrict__ W, int Cin, int Cin_pad,
                             _Float16* __restrict__ Wh, int total) {
    int i = blockIdx.x * 256 + threadIdx.x;
    if (i >= total) return;
    int o = i / Cin_pad, c = i - o * Cin_pad;
    Wh[i] = (c < Cin) ? (_Float16)W[(size_t)o * Cin + c] : (_Float16)0.f;
}

// ---------------------------------------------------------------------------
// MFMA conv with fused IN (stats epilogue + norm-on-load).
// ---------------------------------------------------------------------------
template<bool HAS_POOL, bool NORM_IN, bool STATS>
__global__ __launch_bounds__(256) void conv_mfma_kernel(
    const _Float16* __restrict__ Wh, const float* __restrict__ bias,
    int Cin_pad, int C1,
    const _Float16* __restrict__ Xp,
    const _Float16* __restrict__ X,
    const float* __restrict__ muIn, const float* __restrict__ riIn,
    _Float16* __restrict__ Y,
    int M, int Cout,
    float* __restrict__ psum, float* __restrict__ psq) {
    const int wave = threadIdx.x >> 6;
    const int lane = threadIdx.x & 63;
    const int row  = lane & 15;
    const int kg   = lane >> 4;
    const int m0   = blockIdx.x * 128 + wave * 32;
    const int o0   = blockIdx.y * 64;
    const int mIdx0 = m0 + row;
    const int mIdx1 = m0 + 16 + row;

    float4v acc[2][4];
#pragma unroll
    for (int t = 0; t < 4; ++t) {
        const float* bp = bias + o0 + 16 * t + kg * 4;
        float4v bv4 = (float4v){bp[0], bp[1], bp[2], bp[3]};
        acc[0][t] = bv4;
        acc[1][t] = bv4;
    }
    const int C2 = Cin_pad - C1;
    if (HAS_POOL) {
        const _Float16* pr0 = Xp + (size_t)(mIdx0 >> 5) * C1;
        const _Float16* pr1 = Xp + (size_t)(mIdx1 >> 5) * C1;
        for (int c0 = 0; c0 < C1; c0 += 32) {
            half8v b0 = *(const half8v*)(pr0 + c0 + kg * 8);
            half8v b1 = *(const half8v*)(pr1 + c0 + kg * 8);
#pragma unroll
            for (int t = 0; t < 4; ++t) {
                half8v afr = *(const half8v*)(Wh + (size_t)(o0 + 16 * t + row) * Cin_pad + c0 + kg * 8);
                acc[0][t] = __builtin_amdgcn_mfma_f32_16x16x32_f16(afr, b0, acc[0][t], 0, 0, 0);
                acc[1][t] = __builtin_amdgcn_mfma_f32_16x16x32_f16(afr, b1, acc[1][t], 0, 0, 0);
            }
        }
    }
    const _Float16* xr0 = X + (size_t)mIdx0 * C2;
    const _Float16* xr1 = X + (size_t)mIdx1 * C2;
    for (int c0 = 0; c0 < C2; c0 += 32) {
        half8v b0 = *(const half8v*)(xr0 + c0 + kg * 8);
        half8v b1 = *(const half8v*)(xr1 + c0 + kg * 8);
        if (NORM_IN) {
            const int cb = c0 + kg * 8;
#pragma unroll
            for (int r = 0; r < 8; ++r) {
                float mu = muIn[cb + r], ri = riIn[cb + r];
                b0[r] = (_Float16)fmaxf(((float)b0[r] - mu) * ri, 0.f);
                b1[r] = (_Float16)fmaxf(((float)b1[r] - mu) * ri, 0.f);
            }
        }
#pragma unroll
        for (int t = 0; t < 4; ++t) {
            half8v afr = *(const half8v*)(Wh + (size_t)(o0 + 16 * t + row) * Cin_pad + C1 + c0 + kg * 8);
            acc[0][t] = __builtin_amdgcn_mfma_f32_16x16x32_f16(afr, b0, acc[0][t], 0, 0, 0);
            acc[1][t] = __builtin_amdgcn_mfma_f32_16x16x32_f16(afr, b1, acc[1][t], 0, 0, 0);
        }
    }
#pragma unroll
    for (int w = 0; w < 2; ++w) {
        int mi = (w == 0) ? mIdx0 : mIdx1;
#pragma unroll
        for (int t = 0; t < 4; ++t) {
            half4v hv;
            hv[0] = (_Float16)acc[w][t][0];
            hv[1] = (_Float16)acc[w][t][1];
            hv[2] = (_Float16)acc[w][t][2];
            hv[3] = (_Float16)acc[w][t][3];
            *(half4v*)(Y + (size_t)mi * Cout + o0 + 16 * t + kg * 4) = hv;
        }
    }
    if (STATS) {
        float s[16], q[16];
#pragma unroll
        for (int t = 0; t < 4; ++t)
#pragma unroll
            for (int r = 0; r < 4; ++r) {
                float a0 = acc[0][t][r], a1 = acc[1][t][r];
                s[t * 4 + r] = a0 + a1;
                q[t * 4 + r] = fmaf(a0, a0, a1 * a1);
            }
#pragma unroll
        for (int mask = 1; mask <= 8; mask <<= 1) {
#pragma unroll
            for (int i = 0; i < 16; ++i) {
                s[i] += __shfl_xor(s[i], mask);
                q[i] += __shfl_xor(q[i], mask);
            }
        }
        if (row == 0) {
            int mrow = blockIdx.x * 4 + wave;
            float* ps = psum + (size_t)mrow * Cout + o0;
            float* pq = psq  + (size_t)mrow * Cout + o0;
#pragma unroll
            for (int t = 0; t < 4; ++t)
#pragma unroll
                for (int r = 0; r < 4; ++r) {
                    ps[16 * t + kg * 4 + r] = s[t * 4 + r];
                    pq[16 * t + kg * 4 + r] = q[t * 4 + r];
                }
        }
    }
}

// in_fin: one BLOCK per channel; deterministic tree reduce.
__global__ __launch_bounds__(256) void in_fin_kernel(const float* __restrict__ psum,
                                                     const float* __restrict__ psq,
                                                     int C, int rows, int M,
                                                     float* __restrict__ mean,
                                                     float* __restrict__ rinv) {
    int c = blockIdx.x;
    int tid = threadIdx.x;
    float s = 0.f, q = 0.f;
    for (int r = tid; r < rows; r += 256) {
        s += psum[(size_t)r * C + c];
        q += psq [(size_t)r * C + c];
    }
#pragma unroll
    for (int off = 32; off >= 1; off >>= 1) {
        s += __shfl_down(s, off);
        q += __shfl_down(q, off);
    }
    __shared__ float sS[4], sQ[4];
    if ((tid & 63) == 0) { sS[tid >> 6] = s; sQ[tid >> 6] = q; }
    __syncthreads();
    if (tid == 0) {
        float fs = sS[0] + sS[1] + sS[2] + sS[3];
        float fq = sQ[0] + sQ[1] + sQ[2] + sQ[3];
        float mu  = fs / (float)M;
        float var = fq / (float)M - mu * mu;
        mean[c] = mu;
        rinv[c] = rsqrtf(fmaxf(var, 0.f) + EPS_F);
    }
}

// pooled[s][c] = max_k Y[(s*32+k)][c]
__global__ void maxk_kernel(const _Float16* __restrict__ Y, int C,
                            _Float16* __restrict__ pooled, int total) {
    int i = blockIdx.x * 256 + threadIdx.x;
    if (i >= total) return;
    int c = i % C;
    int s = i / C;
    const _Float16* base = Y + (size_t)s * 32 * C + c;
    float mx = (float)base[0];
#pragma unroll 8
    for (int k = 1; k < K_NBR; ++k) mx = fmaxf(mx, (float)base[(size_t)k * C]);
    pooled[(size_t)s * C + c] = (_Float16)mx;
}

// out_f[o][s] = relu((max_k RD - mu)*rinv); + f16 transposed feature copy.
__global__ void maxk_out_in_kernel(const _Float16* __restrict__ Y, int C, int S,
                                   const float* __restrict__ mean, const float* __restrict__ rinv,
                                   float* __restrict__ outf_b, _Float16* __restrict__ ftr_out,
                                   int total) {
    int i = blockIdx.x * 256 + threadIdx.x;
    if (i >= total) return;
    int o = i % C;
    int s = i / C;
    const _Float16* base = Y + (size_t)s * 32 * C + o;
    float mx = (float)base[0];
#pragma unroll 8
    for (int k = 1; k < K_NBR; ++k) mx = fmaxf(mx, (float)base[(size_t)k * C]);
    float val = fmaxf((mx - mean[o]) * rinv[o], 0.f);
    outf_b[(size_t)o * S + s] = val;
    if (ftr_out) ftr_out[i] = (_Float16)val;
}

// ---------------------------------------------------------------------------
struct StageArgs {
    const float *P, *F, *CTR;
    const _Float16* FTR;
    const int *NBR, *IDX;
    int N, S, C, e, Cin_pad;
    const _Float16 *Wa1, *Wb1, *Wa2, *Wb2;
    const float *ba1, *bb1, *ba2, *bb2;
    float* OUTF;
    _Float16* FTR_OUT;
};

static void run_conv_stage(const StageArgs& a, hipStream_t stream,
                           uint8_t* R1, uint8_t* R2, size_t xo_off,
                           _Float16* pooled, float* cf_ws, _Float16* cfh_ws,
                           float* psum, float* psq, float* mean_ws, float* rinv_ws) {
    const int M = a.S * K_NBR;
    const int e = a.e;
    const int srows = M / 32;
    _Float16* x0 = (_Float16*)R1;
    _Float16* RA = (_Float16*)(R1 + xo_off);
    _Float16* RC = (_Float16*)R1;
    _Float16* RB = (_Float16*)R2;
    _Float16* RD = (_Float16*)R2;
    for (int b = 0; b < 4; ++b) {
        const float* p_b   = a.P + (size_t)b * a.N * 3;
        const float* ctr_b = a.CTR + (size_t)b * a.S * 3;
        const int*   nbr_b = a.NBR + (size_t)b * a.S * K_NBR;
        const int*   idx_b = a.IDX + (size_t)b * a.S;
        float*       outf_b= a.OUTF + (size_t)b * e * a.S;

        if (a.FTR == nullptr) {
            const float* f_b = a.F + (size_t)b * a.C * a.N;
            gather_cf_kernel<<<(a.C * a.S + 255) / 256, 256, 0, stream>>>(f_b, idx_b, a.N, a.S, cf_ws, a.C * a.S);
            build_x_kernel<<<M / 256, 256, 0, stream>>>(p_b, f_b, ctr_b, cf_ws, nbr_b,
                                                        a.N, a.S, a.C, a.Cin_pad, M, x0);
        } else {
            const _Float16* ftr_b = a.FTR + (size_t)b * a.N * a.C;
            gather_cf2_kernel<<<(a.C * a.S + 255) / 256, 256, 0, stream>>>(ftr_b, idx_b, a.C, a.S, cfh_ws, a.C * a.S);
            build_x2_kernel<<<M / 256, 256, 0, stream>>>(p_b, ftr_b, ctr_b, cfh_ws, nbr_b,
                                                         a.S, a.C, a.Cin_pad, M, x0);
        }

        conv_mfma_kernel<false, false, true><<<dim3(M / 128, e / 64), 256, 0, stream>>>(
            a.Wa1, a.ba1, a.Cin_pad, 0, nullptr, x0, nullptr, nullptr, RA, M, e, psum, psq);
        in_fin_kernel<<<e, 256, 0, stream>>>(psum, psq, e, srows, M, mean_ws, rinv_ws);
        conv_mfma_kernel<false, true, false><<<dim3(M / 128, e / 64), 256, 0, stream>>>(
            a.Wb1, a.bb1, e, 0, nullptr, RA, mean_ws, rinv_ws, RB, M, e, nullptr, nullptr);
        maxk_kernel<<<(e * (M / 32) + 255) / 256, 256, 0, stream>>>(RB, e, pooled, e * (M / 32));
        conv_mfma_kernel<true, false, true><<<dim3(M / 128, (2 * e) / 64), 256, 0, stream>>>(
            a.Wa2, a.ba2, 2 * e, e, pooled, RB, nullptr, nullptr, RC, M, 2 * e, psum, psq);
        in_fin_kernel<<<2 * e, 256, 0, stream>>>(psum, psq, 2 * e, srows, M, mean_ws, rinv_ws);
        conv_mfma_kernel<false, true, true><<<dim3(M / 128, e / 64), 256, 0, stream>>>(
            a.Wb2, a.bb2, 2 * e, 0, nullptr, RC, mean_ws, rinv_ws, RD, M, e, psum, psq);
        in_fin_kernel<<<e, 256, 0, stream>>>(psum, psq, e, srows, M, mean_ws, rinv_ws);
        _Float16* ftr_b_out = a.FTR_OUT ? a.FTR_OUT + (size_t)b * a.S * e : nullptr;
        maxk_out_in_kernel<<<(e * a.S + 255) / 256, 256, 0, stream>>>(RD, e, a.S, mean_ws, rinv_ws,
                                                                      outf_b, ftr_b_out, e * a.S);
    }
}

extern "C" void kernel_launch(void* const* d_in, const int* in_sizes, int n_in,
                              void* d_out, int out_size, void* d_ws, size_t ws_size,
                              hipStream_t stream) {
    const float* p    = (const float*)d_in[0];
    const float* f    = (const float*)d_in[1];
    const float* w1a1 = (const float*)d_in[2];
    const float* b1a1 = (const float*)d_in[3];
    const float* w1b1 = (const float*)d_in[4];
    const float* b1b1 = (const float*)d_in[5];
    const float* w1a2 = (const float*)d_in[6];
    const float* b1a2 = (const float*)d_in[7];
    const float* w1b2 = (const float*)d_in[8];
    const float* b1b2 = (const float*)d_in[9];
    const float* w2a1 = (const float*)d_in[10];
    const float* b2a1 = (const float*)d_in[11];
    const float* w2b1 = (const float*)d_in[12];
    const float* b2b1 = (const float*)d_in[13];
    const float* w2a2 = (const float*)d_in[14];
    const float* b2a2 = (const float*)d_in[15];
    const float* w2b2 = (const float*)d_in[16];
    const float* b2b2 = (const float*)d_in[17];

    float* out   = (float*)d_out;
    float* outp1 = out;
    float* outf1 = out + 24576;
    float* outp2 = outf1 + 1572864;
    float* outf2 = outp2 + 6144;

    uint8_t* wsp = (uint8_t*)d_ws;
    uint8_t* wend = wsp + ws_size;
    auto alloc = [&](size_t bytes) -> void* {
        void* r = wsp;
        wsp += (bytes + 255) & ~(size_t)255;
        return r;
    };
    int*   idx1   = (int*)  alloc((size_t)4 * 2048 * 4);
    int*   idx2   = (int*)  alloc((size_t)4 * 512 * 4);
    int*   nbr1   = (int*)  alloc((size_t)4 * 2048 * K_NBR * 4);
    int*   nbr2   = (int*)  alloc((size_t)4 * 512 * K_NBR * 4);
    float* cf_ws  = (float*)alloc((size_t)192 * 512 * 4);
    _Float16* cfh_ws = (_Float16*)alloc((size_t)512 * 192 * 2);
    float* mean_ws= (float*)alloc((size_t)768 * 4);
    float* rinv_ws= (float*)alloc((size_t)768 * 4);
    float* psum   = (float*)alloc((size_t)2048 * 768 * 4);
    float* psq    = (float*)alloc((size_t)2048 * 768 * 4);
    _Float16* pooled = (_Float16*)alloc((size_t)2048 * 384 * 2);
    _Float16* ftr1   = (_Float16*)alloc((size_t)4 * 2048 * 192 * 2);
    _Float16* h1a1 = (_Float16*)alloc((size_t)192 * 32  * 2);
    _Float16* h1b1 = (_Float16*)alloc((size_t)192 * 192 * 2);
    _Float16* h1a2 = (_Float16*)alloc((size_t)384 * 384 * 2);
    _Float16* h1b2 = (_Float16*)alloc((size_t)192 * 384 * 2);
    _Float16* h2a1 = (_Float16*)alloc((size_t)384 * 224 * 2);
    _Float16* h2b1 = (_Float16*)alloc((size_t)384 * 384 * 2);
    _Float16* h2a2 = (_Float16*)alloc((size_t)768 * 768 * 2);
    _Float16* h2b2 = (_Float16*)alloc((size_t)384 * 768 * 2);
    if (wsp > wend) return;

    auto wc = [&](const float* W, int Cin, int Cpad, int Cout, _Float16* Wh) {
        int tot = Cout * Cpad;
        wconv_kernel<<<(tot + 255) / 256, 256, 0, stream>>>(W, Cin, Cpad, Wh, tot);
    };
    wc(w1a1, 6,   32,  192, h1a1);
    wc(w1b1, 192, 192, 192, h1b1);
    wc(w1a2, 384, 384, 384, h1a2);
    wc(w1b2, 384, 384, 192, h1b2);
    wc(w2a1, 195, 224, 384, h2a1);
    wc(w2b1, 384, 384, 384, h2b1);
    wc(w2a2, 768, 768, 768, h2a2);
    wc(w2b2, 768, 768, 384, h2b2);

    // geometry: verified-exact FPS (stage1 MINW=1 -> no register spill)
    fps_kernel<32, 1><<<4, 256, 0, stream>>>(p, 8192, 2048, idx1, outp1);
    ball_query_kernel<<<(4 * 2048) / 4, 256, 0, stream>>>(p, outp1, 8192, 2048, nbr1);
    fps_kernel<8, 2><<<4, 256, 0, stream>>>(outp1, 2048, 512, idx2, outp2);
    ball_query_kernel<<<(4 * 512) / 4, 256, 0, stream>>>(outp1, outp2, 2048, 512, nbr2);

    const size_t MB = (size_t)1024 * 1024;
    uint8_t* R1 = (uint8_t*)alloc(48 * MB);
    uint8_t* R2 = (uint8_t*)alloc(24 * MB);
    if (wsp > wend) return;

    StageArgs s1 { p, f, outp1, nullptr, nbr1, idx1, 8192, 2048, 3, 192, 32,
                   h1a1, h1b1, h1a2, h1b2, b1a1, b1b1, b1a2, b1b2, outf1, ftr1 };
    StageArgs s2 { outp1, nullptr, outp2, ftr1, nbr2, idx2, 2048, 512, 192, 384, 224,
                   h2a1, h2b1, h2a2, h2b2, b2a1, b2b1, b2a2, b2b2, outf2, nullptr };

    run_conv_stage(s1, stream, R1, R2, 8 * MB, pooled, cf_ws, cfh_ws, psum, psq, mean_ws, rinv_ws);
    run_conv_stage(s2, stream, R1, R2, 8 * MB, pooled, cf_ws, cfh_ws, psum, psq, mean_ws, rinv_ws);
}

// Round 26
// 5725.185 us; speedup vs baseline: 1.2287x; 1.0333x over previous
//
#include <hip/hip_runtime.h>
#include <hip/hip_bf16.h>
#include <hip/hip_fp16.h>
#include <stdint.h>

#define K_NBR 32
#define EPS_F 1e-5f

typedef _Float16 half8v __attribute__((ext_vector_type(8)));
typedef _Float16 half4v __attribute__((ext_vector_type(4)));
typedef float float4v __attribute__((ext_vector_type(4)));

// ---------------------------------------------------------------------------
// FPS: EXACT verified arithmetic (asc-rn direct, smallest-index argmax).
// Serial-path optimizations, all semantics-preserving:
//  - outputs buffered in a 256-slot LDS ring, flushed every 256 steps
//    (removes tid0's global stores from the per-step barrier drain)
//  - winner coords from an LDS mirror (broadcast ds_read, no global load)
//  - argmax scan fused into the update loop as 4 independent chains
//    (ascending j within chain, ascending chain merge = same tie-breaks)
// ---------------------------------------------------------------------------
template<int PPT, int MINW>
__global__ __launch_bounds__(256, MINW) void fps_kernel(const float* __restrict__ p, int N, int S,
                                                        int* __restrict__ idx_out,
                                                        float* __restrict__ centers) {
    constexpr int CH = PPT / 4;
    constexpr int NPT = PPT * 256;
    const int b = blockIdx.x;
    const int tid = threadIdx.x;
    const float* pb = p + (size_t)b * N * 3;

    __shared__ float m_x[NPT], m_y[NPT], m_z[NPT];
    __shared__ float s_val[2][4];
    __shared__ int   s_idx[2][4];
    __shared__ int   r_i[256];
    __shared__ float r_x[256], r_y[256], r_z[256];

    float px[PPT], py[PPT], pz[PPT], dist[PPT];
    float v[4]; int ixl[4];
    const float l0x = pb[0], l0y = pb[1], l0z = pb[2];
#pragma unroll
    for (int j = 0; j < PPT; ++j) {
        int i = j * 256 + tid;
        px[j] = pb[(size_t)i * 3 + 0];
        py[j] = pb[(size_t)i * 3 + 1];
        pz[j] = pb[(size_t)i * 3 + 2];
        m_x[i] = px[j]; m_y[i] = py[j]; m_z[i] = pz[j];
        float dx = __fsub_rn(px[j], l0x);
        float dy = __fsub_rn(py[j], l0y);
        float dz = __fsub_rn(pz[j], l0z);
        dist[j] = __fadd_rn(__fadd_rn(__fmul_rn(dx, dx), __fmul_rn(dy, dy)), __fmul_rn(dz, dz));
        constexpr int KJ0 = 0;  (void)KJ0;
        int k = j / CH;
        if ((j % CH) == 0) { v[k] = dist[j]; ixl[k] = j * 256 + tid; }
        else if (dist[j] > v[k]) { v[k] = dist[j]; ixl[k] = j * 256 + tid; }
    }

    if (tid == 0) {
        idx_out[(size_t)b * S] = 0;
        centers[((size_t)b * S) * 3 + 0] = l0x;
        centers[((size_t)b * S) * 3 + 1] = l0y;
        centers[((size_t)b * S) * 3 + 2] = l0z;
    }
    __syncthreads();   // mirror visibility

    for (int t = 1; t < S; ++t) {
        const int pp = t & 1;
        // merge chains (ascending k; indices in chain k < chain k+1 for same tid)
        float bv = v[0]; int bi = ixl[0];
#pragma unroll
        for (int k = 1; k < 4; ++k) if (v[k] > bv) { bv = v[k]; bi = ixl[k]; }
        // wave argmax (max value, min index tiebreak)
#pragma unroll
        for (int off = 32; off >= 1; off >>= 1) {
            float ov = __shfl_down(bv, off);
            int   oi = __shfl_down(bi, off);
            if (ov > bv || (ov == bv && oi < bi)) { bv = ov; bi = oi; }
        }
        if ((tid & 63) == 0) { s_val[pp][tid >> 6] = bv; s_idx[pp][tid >> 6] = bi; }
        __syncthreads();
        // periodic ring flush (slots for steps [t-256, t-1]; slot == tid)
        if ((t & 255) == 0) {
            int s0 = (t - 256) + tid;
            if (s0 >= 1) {
                idx_out[(size_t)b * S + s0] = r_i[tid];
                centers[((size_t)b * S + s0) * 3 + 0] = r_x[tid];
                centers[((size_t)b * S + s0) * 3 + 1] = r_y[tid];
                centers[((size_t)b * S + s0) * 3 + 2] = r_z[tid];
            }
            __syncthreads();   // flush reads complete before slot reuse below
        }
        bv = s_val[pp][0]; bi = s_idx[pp][0];
#pragma unroll
        for (int w = 1; w < 4; ++w)
            if (s_val[pp][w] > bv || (s_val[pp][w] == bv && s_idx[pp][w] < bi)) { bv = s_val[pp][w]; bi = s_idx[pp][w]; }
        // winner coords: broadcast LDS mirror read (exact same bits as global)
        const float lx = m_x[bi];
        const float ly = m_y[bi];
        const float lz = m_z[bi];
        if (tid == 0) {
            r_i[t & 255] = bi;
            r_x[t & 255] = lx; r_y[t & 255] = ly; r_z[t & 255] = lz;
        }
        // fused update + chain scan
#pragma unroll
        for (int j = 0; j < PPT; ++j) {
            float dx = __fsub_rn(px[j], lx);
            float dy = __fsub_rn(py[j], ly);
            float dz = __fsub_rn(pz[j], lz);
            float nd = __fadd_rn(__fadd_rn(__fmul_rn(dx, dx), __fmul_rn(dy, dy)), __fmul_rn(dz, dz));
            dist[j] = fminf(dist[j], nd);
            int k = j / CH;
            if ((j % CH) == 0) { v[k] = dist[j]; ixl[k] = j * 256 + tid; }
            else if (dist[j] > v[k]) { v[k] = dist[j]; ixl[k] = j * 256 + tid; }
        }
    }
    __syncthreads();
    // tail flush: steps [base, S-1], slot == tid
    {
        int base = (S - 1) & ~255;
        int s0 = base + tid;
        if (s0 >= 1 && s0 <= S - 1) {
            idx_out[(size_t)b * S + s0] = r_i[tid];
            centers[((size_t)b * S + s0) * 3 + 0] = r_x[tid];
            centers[((size_t)b * S + s0) * 3 + 1] = r_y[tid];
            centers[((size_t)b * S + s0) * 3 + 2] = r_z[tid];
        }
    }
}

// ---------------------------------------------------------------------------
// Ball query — BYTE-IDENTICAL to the passing round-17 kernel. DO NOT TOUCH.
// ---------------------------------------------------------------------------
__global__ __launch_bounds__(256) void ball_query_kernel(const float* __restrict__ pts,
                                                         const float* __restrict__ ctr,
                                                         int N, int S, int* __restrict__ nbr) {
    int gw   = (int)((blockIdx.x * 256 + threadIdx.x) >> 6);
    int lane = threadIdx.x & 63;
    int b = gw / S;
    int s = gw - b * S;
    const float* pb = pts + (size_t)b * N * 3;
    const float c0 = ctr[((size_t)b * S + s) * 3 + 0];
    const float c1 = ctr[((size_t)b * S + s) * 3 + 1];
    const float c2 = ctr[((size_t)b * S + s) * 3 + 2];
    const float cn = __fadd_rn(__fadd_rn(__fmul_rn(c0, c0), __fmul_rn(c2, c2)), __fmul_rn(c1, c1));
    const float R2 = (float)(0.1 * 0.1);
    int* out = nbr + (size_t)gw * K_NBR;

    int cnt = 0;
    int firstIdx = 0;
    bool haveFirst = false;
    for (int base = 0; base < N && cnt < K_NBR; base += 64) {
        int i = base + lane;
        float x = pb[(size_t)i * 3 + 0];
        float y = pb[(size_t)i * 3 + 1];
        float z = pb[(size_t)i * 3 + 2];
        float pn = __fadd_rn(__fadd_rn(__fmul_rn(x, x), __fmul_rn(z, z)), __fmul_rn(y, y));
        float pr0 = __fmul_rn(c0, x);
        float pr1 = __fmul_rn(c1, y);
        float pr2 = __fmul_rn(c2, z);
        float dt  = __fadd_rn(__fadd_rn(pr0, pr2), pr1);
        float d2 = __fsub_rn(__fadd_rn(cn, pn), __fmul_rn(2.0f, dt));
        bool inR = d2 < R2;
        unsigned long long mask = __ballot(inR);
        if (mask) {
            if (!haveFirst) { haveFirst = true; firstIdx = base + __builtin_ctzll(mask); }
            int rank = __popcll(mask & ((1ull << lane) - 1ull));
            if (inR) {
                int slot = cnt + rank;
                if (slot < K_NBR) out[slot] = i;
            }
            cnt += (int)__popcll(mask);
        }
    }
    if (cnt < K_NBR) {
        for (int sl = cnt + lane; sl < K_NBR; sl += 64) out[sl] = firstIdx;
    }
}

// ---------------------------------------------------------------------------
__global__ void gather_cf_kernel(const float* __restrict__ f_b, const int* __restrict__ idx_b,
                                 int N, int S, float* __restrict__ cf, int total) {
    int i = blockIdx.x * 256 + threadIdx.x;
    if (i >= total) return;
    int s = i % S;
    int c = i / S;
    cf[i] = f_b[(size_t)c * N + idx_b[s]];
}

__global__ void build_x_kernel(const float* __restrict__ p_b, const float* __restrict__ f_b,
                               const float* __restrict__ ctr_b, const float* __restrict__ cf,
                               const int* __restrict__ nbr_b,
                               int N, int S, int C, int Cin_pad, int M,
                               _Float16* __restrict__ x) {
    int m = blockIdx.x * 256 + threadIdx.x;
    if (m >= M) return;
    int s = m / K_NBR;
    int n = nbr_b[m];
    const float* pp = p_b + (size_t)n * 3;
    const float* cc = ctr_b + (size_t)s * 3;
    _Float16* row = x + (size_t)m * Cin_pad;
    row[0] = (_Float16)__fsub_rn(pp[0], cc[0]);
    row[1] = (_Float16)__fsub_rn(pp[1], cc[1]);
    row[2] = (_Float16)__fsub_rn(pp[2], cc[2]);
    for (int c = 0; c < C; ++c)
        row[3 + c] = (_Float16)__fsub_rn(f_b[(size_t)c * N + n], cf[(size_t)c * S + s]);
    for (int c = 3 + C; c < Cin_pad; ++c) row[c] = (_Float16)0.f;
}

__global__ void gather_cf2_kernel(const _Float16* __restrict__ ftr, const int* __restrict__ idx_b,
                                  int C, int S, _Float16* __restrict__ cfh, int total) {
    int i = blockIdx.x * 256 + threadIdx.x;
    if (i >= total) return;
    int c = i % C;
    int s = i / C;
    cfh[i] = ftr[(size_t)idx_b[s] * C + c];
}

__global__ void build_x2_kernel(const float* __restrict__ p_b, const _Float16* __restrict__ ftr,
                                const float* __restrict__ ctr_b, const _Float16* __restrict__ cfh,
                                const int* __restrict__ nbr_b,
                                int S, int C, int Cin_pad, int M,
                                _Float16* __restrict__ x) {
    int m = blockIdx.x * 256 + threadIdx.x;
    if (m >= M) return;
    int s = m / K_NBR;
    int n = nbr_b[m];
    const float* pp = p_b + (size_t)n * 3;
    const float* cc = ctr_b + (size_t)s * 3;
    _Float16* row = x + (size_t)m * Cin_pad;
    row[0] = (_Float16)__fsub_rn(pp[0], cc[0]);
    row[1] = (_Float16)__fsub_rn(pp[1], cc[1]);
    row[2] = (_Float16)__fsub_rn(pp[2], cc[2]);
    const _Float16* fr = ftr + (size_t)n * C;
    const _Float16* cr = cfh + (size_t)s * C;
    for (int c = 0; c < C; ++c)
        row[3 + c] = (_Float16)__fsub_rn((float)fr[c], (float)cr[c]);
    for (int c = 3 + C; c < Cin_pad; ++c) row[c] = (_Float16)0.f;
}

__global__ void wconv_kernel(const float* __restrict__ W, int Cin, int Cin_pad,
                             _Float16* __restrict__ Wh, int total) {
    int i = blockIdx.x * 256 + threadIdx.x;
    if (i >= total) return;
    int o = i / Cin_pad, c = i - o * Cin_pad;
    Wh[i] = (c < Cin) ? (_Float16)W[(size_t)o * Cin + c] : (_Float16)0.f;
}

// ---------------------------------------------------------------------------
// MFMA conv with fused IN (stats epilogue + norm-on-load).
// ---------------------------------------------------------------------------
template<bool HAS_POOL, bool NORM_IN, bool STATS>
__global__ __launch_bounds__(256) void conv_mfma_kernel(
    const _Float16* __restrict__ Wh, const float* __restrict__ bias,
    int Cin_pad, int C1,
    const _Float16* __restrict__ Xp,
    const _Float16* __restrict__ X,
    const float* __restrict__ muIn, const float* __restrict__ riIn,
    _Float16* __restrict__ Y,
    int M, int Cout,
    float* __restrict__ psum, float* __restrict__ psq) {
    const int wave = threadIdx.x >> 6;
    const int lane = threadIdx.x & 63;
    const int row  = lane & 15;
    const int kg   = lane >> 4;
    const int m0   = blockIdx.x * 128 + wave * 32;
    const int o0   = blockIdx.y * 64;
    const int mIdx0 = m0 + row;
    const int mIdx1 = m0 + 16 + row;

    float4v acc[2][4];
#pragma unroll
    for (int t = 0; t < 4; ++t) {
        const float* bp = bias + o0 + 16 * t + kg * 4;
        float4v bv4 = (float4v){bp[0], bp[1], bp[2], bp[3]};
        acc[0][t] = bv4;
        acc[1][t] = bv4;
    }
    const int C2 = Cin_pad - C1;
    if (HAS_POOL) {
        const _Float16* pr0 = Xp + (size_t)(mIdx0 >> 5) * C1;
        const _Float16* pr1 = Xp + (size_t)(mIdx1 >> 5) * C1;
        for (int c0 = 0; c0 < C1; c0 += 32) {
            half8v b0 = *(const half8v*)(pr0 + c0 + kg * 8);
            half8v b1 = *(const half8v*)(pr1 + c0 + kg * 8);
#pragma unroll
            for (int t = 0; t < 4; ++t) {
                half8v afr = *(const half8v*)(Wh + (size_t)(o0 + 16 * t + row) * Cin_pad + c0 + kg * 8);
                acc[0][t] = __builtin_amdgcn_mfma_f32_16x16x32_f16(afr, b0, acc[0][t], 0, 0, 0);
                acc[1][t] = __builtin_amdgcn_mfma_f32_16x16x32_f16(afr, b1, acc[1][t], 0, 0, 0);
            }
        }
    }
    const _Float16* xr0 = X + (size_t)mIdx0 * C2;
    const _Float16* xr1 = X + (size_t)mIdx1 * C2;
    for (int c0 = 0; c0 < C2; c0 += 32) {
        half8v b0 = *(const half8v*)(xr0 + c0 + kg * 8);
        half8v b1 = *(const half8v*)(xr1 + c0 + kg * 8);
        if (NORM_IN) {
            const int cb = c0 + kg * 8;
#pragma unroll
            for (int r = 0; r < 8; ++r) {
                float mu = muIn[cb + r], ri = riIn[cb + r];
                b0[r] = (_Float16)fmaxf(((float)b0[r] - mu) * ri, 0.f);
                b1[r] = (_Float16)fmaxf(((float)b1[r] - mu) * ri, 0.f);
            }
        }
#pragma unroll
        for (int t = 0; t < 4; ++t) {
            half8v afr = *(const half8v*)(Wh + (size_t)(o0 + 16 * t + row) * Cin_pad + C1 + c0 + kg * 8);
            acc[0][t] = __builtin_amdgcn_mfma_f32_16x16x32_f16(afr, b0, acc[0][t], 0, 0, 0);
            acc[1][t] = __builtin_amdgcn_mfma_f32_16x16x32_f16(afr, b1, acc[1][t], 0, 0, 0);
        }
    }
#pragma unroll
    for (int w = 0; w < 2; ++w) {
        int mi = (w == 0) ? mIdx0 : mIdx1;
#pragma unroll
        for (int t = 0; t < 4; ++t) {
            half4v hv;
            hv[0] = (_Float16)acc[w][t][0];
            hv[1] = (_Float16)acc[w][t][1];
            hv[2] = (_Float16)acc[w][t][2];
            hv[3] = (_Float16)acc[w][t][3];
            *(half4v*)(Y + (size_t)mi * Cout + o0 + 16 * t + kg * 4) = hv;
        }
    }
    if (STATS) {
        float s[16], q[16];
#pragma unroll
        for (int t = 0; t < 4; ++t)
#pragma unroll
            for (int r = 0; r < 4; ++r) {
                float a0 = acc[0][t][r], a1 = acc[1][t][r];
                s[t * 4 + r] = a0 + a1;
                q[t * 4 + r] = fmaf(a0, a0, a1 * a1);
            }
#pragma unroll
        for (int mask = 1; mask <= 8; mask <<= 1) {
#pragma unroll
            for (int i = 0; i < 16; ++i) {
                s[i] += __shfl_xor(s[i], mask);
                q[i] += __shfl_xor(q[i], mask);
            }
        }
        if (row == 0) {
            int mrow = blockIdx.x * 4 + wave;
            float* ps = psum + (size_t)mrow * Cout + o0;
            float* pq = psq  + (size_t)mrow * Cout + o0;
#pragma unroll
            for (int t = 0; t < 4; ++t)
#pragma unroll
                for (int r = 0; r < 4; ++r) {
                    ps[16 * t + kg * 4 + r] = s[t * 4 + r];
                    pq[16 * t + kg * 4 + r] = q[t * 4 + r];
                }
        }
    }
}

// in_fin: one BLOCK per channel; deterministic tree reduce.
__global__ __launch_bounds__(256) void in_fin_kernel(const float* __restrict__ psum,
                                                     const float* __restrict__ psq,
                                                     int C, int rows, int M,
                                                     float* __restrict__ mean,
                                                     float* __restrict__ rinv) {
    int c = blockIdx.x;
    int tid = threadIdx.x;
    float s = 0.f, q = 0.f;
    for (int r = tid; r < rows; r += 256) {
        s += psum[(size_t)r * C + c];
        q += psq [(size_t)r * C + c];
    }
#pragma unroll
    for (int off = 32; off >= 1; off >>= 1) {
        s += __shfl_down(s, off);
        q += __shfl_down(q, off);
    }
    __shared__ float sS[4], sQ[4];
    if ((tid & 63) == 0) { sS[tid >> 6] = s; sQ[tid >> 6] = q; }
    __syncthreads();
    if (tid == 0) {
        float fs = sS[0] + sS[1] + sS[2] + sS[3];
        float fq = sQ[0] + sQ[1] + sQ[2] + sQ[3];
        float mu  = fs / (float)M;
        float var = fq / (float)M - mu * mu;
        mean[c] = mu;
        rinv[c] = rsqrtf(fmaxf(var, 0.f) + EPS_F);
    }
}

// pooled[s][c] = max_k Y[(s*32+k)][c]
__global__ void maxk_kernel(const _Float16* __restrict__ Y, int C,
                            _Float16* __restrict__ pooled, int total) {
    int i = blockIdx.x * 256 + threadIdx.x;
    if (i >= total) return;
    int c = i % C;
    int s = i / C;
    const _Float16* base = Y + (size_t)s * 32 * C + c;
    float mx = (float)base[0];
#pragma unroll 8
    for (int k = 1; k < K_NBR; ++k) mx = fmaxf(mx, (float)base[(size_t)k * C]);
    pooled[(size_t)s * C + c] = (_Float16)mx;
}

// out_f[o][s] = relu((max_k RD - mu)*rinv); + f16 transposed feature copy.
__global__ void maxk_out_in_kernel(const _Float16* __restrict__ Y, int C, int S,
                                   const float* __restrict__ mean, const float* __restrict__ rinv,
                                   float* __restrict__ outf_b, _Float16* __restrict__ ftr_out,
                                   int total) {
    int i = blockIdx.x * 256 + threadIdx.x;
    if (i >= total) return;
    int o = i % C;
    int s = i / C;
    const _Float16* base = Y + (size_t)s * 32 * C + o;
    float mx = (float)base[0];
#pragma unroll 8
    for (int k = 1; k < K_NBR; ++k) mx = fmaxf(mx, (float)base[(size_t)k * C]);
    float val = fmaxf((mx - mean[o]) * rinv[o], 0.f);
    outf_b[(size_t)o * S + s] = val;
    if (ftr_out) ftr_out[i] = (_Float16)val;
}

// ---------------------------------------------------------------------------
struct StageArgs {
    const float *P, *F, *CTR;
    const _Float16* FTR;
    const int *NBR, *IDX;
    int N, S, C, e, Cin_pad;
    const _Float16 *Wa1, *Wb1, *Wa2, *Wb2;
    const float *ba1, *bb1, *ba2, *bb2;
    float* OUTF;
    _Float16* FTR_OUT;
};

static void run_conv_stage(const StageArgs& a, hipStream_t stream,
                           uint8_t* R1, uint8_t* R2, size_t xo_off,
                           _Float16* pooled, float* cf_ws, _Float16* cfh_ws,
                           float* psum, float* psq, float* mean_ws, float* rinv_ws) {
    const int M = a.S * K_NBR;
    const int e = a.e;
    const int srows = M / 32;
    _Float16* x0 = (_Float16*)R1;
    _Float16* RA = (_Float16*)(R1 + xo_off);
    _Float16* RC = (_Float16*)R1;
    _Float16* RB = (_Float16*)R2;
    _Float16* RD = (_Float16*)R2;
    for (int b = 0; b < 4; ++b) {
        const float* p_b   = a.P + (size_t)b * a.N * 3;
        const float* ctr_b = a.CTR + (size_t)b * a.S * 3;
        const int*   nbr_b = a.NBR + (size_t)b * a.S * K_NBR;
        const int*   idx_b = a.IDX + (size_t)b * a.S;
        float*       outf_b= a.OUTF + (size_t)b * e * a.S;

        if (a.FTR == nullptr) {
            const float* f_b = a.F + (size_t)b * a.C * a.N;
            gather_cf_kernel<<<(a.C * a.S + 255) / 256, 256, 0, stream>>>(f_b, idx_b, a.N, a.S, cf_ws, a.C * a.S);
            build_x_kernel<<<M / 256, 256, 0, stream>>>(p_b, f_b, ctr_b, cf_ws, nbr_b,
                                                        a.N, a.S, a.C, a.Cin_pad, M, x0);
        } else {
            const _Float16* ftr_b = a.FTR + (size_t)b * a.N * a.C;
            gather_cf2_kernel<<<(a.C * a.S + 255) / 256, 256, 0, stream>>>(ftr_b, idx_b, a.C, a.S, cfh_ws, a.C * a.S);
            build_x2_kernel<<<M / 256, 256, 0, stream>>>(p_b, ftr_b, ctr_b, cfh_ws, nbr_b,
                                                         a.S, a.C, a.Cin_pad, M, x0);
        }

        conv_mfma_kernel<false, false, true><<<dim3(M / 128, e / 64), 256, 0, stream>>>(
            a.Wa1, a.ba1, a.Cin_pad, 0, nullptr, x0, nullptr, nullptr, RA, M, e, psum, psq);
        in_fin_kernel<<<e, 256, 0, stream>>>(psum, psq, e, srows, M, mean_ws, rinv_ws);
        conv_mfma_kernel<false, true, false><<<dim3(M / 128, e / 64), 256, 0, stream>>>(
            a.Wb1, a.bb1, e, 0, nullptr, RA, mean_ws, rinv_ws, RB, M, e, nullptr, nullptr);
        maxk_kernel<<<(e * (M / 32) + 255) / 256, 256, 0, stream>>>(RB, e, pooled, e * (M / 32));
        conv_mfma_kernel<true, false, true><<<dim3(M / 128, (2 * e) / 64), 256, 0, stream>>>(
            a.Wa2, a.ba2, 2 * e, e, pooled, RB, nullptr, nullptr, RC, M, 2 * e, psum, psq);
        in_fin_kernel<<<2 * e, 256, 0, stream>>>(psum, psq, 2 * e, srows, M, mean_ws, rinv_ws);
        conv_mfma_kernel<false, true, true><<<dim3(M / 128, e / 64), 256, 0, stream>>>(
            a.Wb2, a.bb2, 2 * e, 0, nullptr, RC, mean_ws, rinv_ws, RD, M, e, psum, psq);
        in_fin_kernel<<<e, 256, 0, stream>>>(psum, psq, e, srows, M, mean_ws, rinv_ws);
        _Float16* ftr_b_out = a.FTR_OUT ? a.FTR_OUT + (size_t)b * a.S * e : nullptr;
        maxk_out_in_kernel<<<(e * a.S + 255) / 256, 256, 0, stream>>>(RD, e, a.S, mean_ws, rinv_ws,
                                                                      outf_b, ftr_b_out, e * a.S);
    }
}

extern "C" void kernel_launch(void* const* d_in, const int* in_sizes, int n_in,
                              void* d_out, int out_size, void* d_ws, size_t ws_size,
                              hipStream_t stream) {
    const float* p    = (const float*)d_in[0];
    const float* f    = (const float*)d_in[1];
    const float* w1a1 = (const float*)d_in[2];
    const float* b1a1 = (const float*)d_in[3];
    const float* w1b1 = (const float*)d_in[4];
    const float* b1b1 = (const float*)d_in[5];
    const float* w1a2 = (const float*)d_in[6];
    const float* b1a2 = (const float*)d_in[7];
    const float* w1b2 = (const float*)d_in[8];
    const float* b1b2 = (const float*)d_in[9];
    const float* w2a1 = (const float*)d_in[10];
    const float* b2a1 = (const float*)d_in[11];
    const float* w2b1 = (const float*)d_in[12];
    const float* b2b1 = (const float*)d_in[13];
    const float* w2a2 = (const float*)d_in[14];
    const float* b2a2 = (const float*)d_in[15];
    const float* w2b2 = (const float*)d_in[16];
    const float* b2b2 = (const float*)d_in[17];

    float* out   = (float*)d_out;
    float* outp1 = out;
    float* outf1 = out + 24576;
    float* outp2 = outf1 + 1572864;
    float* outf2 = outp2 + 6144;

    uint8_t* wsp = (uint8_t*)d_ws;
    uint8_t* wend = wsp + ws_size;
    auto alloc = [&](size_t bytes) -> void* {
        void* r = wsp;
        wsp += (bytes + 255) & ~(size_t)255;
        return r;
    };
    int*   idx1   = (int*)  alloc((size_t)4 * 2048 * 4);
    int*   idx2   = (int*)  alloc((size_t)4 * 512 * 4);
    int*   nbr1   = (int*)  alloc((size_t)4 * 2048 * K_NBR * 4);
    int*   nbr2   = (int*)  alloc((size_t)4 * 512 * K_NBR * 4);
    float* cf_ws  = (float*)alloc((size_t)192 * 512 * 4);
    _Float16* cfh_ws = (_Float16*)alloc((size_t)512 * 192 * 2);
    float* mean_ws= (float*)alloc((size_t)768 * 4);
    float* rinv_ws= (float*)alloc((size_t)768 * 4);
    float* psum   = (float*)alloc((size_t)2048 * 768 * 4);
    float* psq    = (float*)alloc((size_t)2048 * 768 * 4);
    _Float16* pooled = (_Float16*)alloc((size_t)2048 * 384 * 2);
    _Float16* ftr1   = (_Float16*)alloc((size_t)4 * 2048 * 192 * 2);
    _Float16* h1a1 = (_Float16*)alloc((size_t)192 * 32  * 2);
    _Float16* h1b1 = (_Float16*)alloc((size_t)192 * 192 * 2);
    _Float16* h1a2 = (_Float16*)alloc((size_t)384 * 384 * 2);
    _Float16* h1b2 = (_Float16*)alloc((size_t)192 * 384 * 2);
    _Float16* h2a1 = (_Float16*)alloc((size_t)384 * 224 * 2);
    _Float16* h2b1 = (_Float16*)alloc((size_t)384 * 384 * 2);
    _Float16* h2a2 = (_Float16*)alloc((size_t)768 * 768 * 2);
    _Float16* h2b2 = (_Float16*)alloc((size_t)384 * 768 * 2);
    if (wsp > wend) return;

    auto wc = [&](const float* W, int Cin, int Cpad, int Cout, _Float16* Wh) {
        int tot = Cout * Cpad;
        wconv_kernel<<<(tot + 255) / 256, 256, 0, stream>>>(W, Cin, Cpad, Wh, tot);
    };
    wc(w1a1, 6,   32,  192, h1a1);
    wc(w1b1, 192, 192, 192, h1b1);
    wc(w1a2, 384, 384, 384, h1a2);
    wc(w1b2, 384, 384, 192, h1b2);
    wc(w2a1, 195, 224, 384, h2a1);
    wc(w2b1, 384, 384, 384, h2b1);
    wc(w2a2, 768, 768, 768, h2a2);
    wc(w2b2, 768, 768, 384, h2b2);

    // geometry: verified-exact FPS (deferred outputs + LDS mirror) + frozen BQ
    fps_kernel<32, 1><<<4, 256, 0, stream>>>(p, 8192, 2048, idx1, outp1);
    ball_query_kernel<<<(4 * 2048) / 4, 256, 0, stream>>>(p, outp1, 8192, 2048, nbr1);
    fps_kernel<8, 1><<<4, 256, 0, stream>>>(outp1, 2048, 512, idx2, outp2);
    ball_query_kernel<<<(4 * 512) / 4, 256, 0, stream>>>(outp1, outp2, 2048, 512, nbr2);

    const size_t MB = (size_t)1024 * 1024;
    uint8_t* R1 = (uint8_t*)alloc(48 * MB);
    uint8_t* R2 = (uint8_t*)alloc(24 * MB);
    if (wsp > wend) return;

    StageArgs s1 { p, f, outp1, nullptr, nbr1, idx1, 8192, 2048, 3, 192, 32,
                   h1a1, h1b1, h1a2, h1b2, b1a1, b1b1, b1a2, b1b2, outf1, ftr1 };
    StageArgs s2 { outp1, nullptr, outp2, ftr1, nbr2, idx2, 2048, 512, 192, 384, 224,
                   h2a1, h2b1, h2a2, h2b2, b2a1, b2b1, b2a2, b2b2, outf2, nullptr };

    run_conv_stage(s1, stream, R1, R2, 8 * MB, pooled, cf_ws, cfh_ws, psum, psq, mean_ws, rinv_ws);
    run_conv_stage(s2, stream, R1, R2, 8 * MB, pooled, cf_ws, cfh_ws, psum, psq, mean_ws, rinv_ws);
}